// Round 4
// baseline (594.860 us; speedup 1.0000x reference)
//
#include <hip/hip_runtime.h>

typedef unsigned short u16;
typedef short bf16x8 __attribute__((ext_vector_type(8)));
typedef float f32x4 __attribute__((ext_vector_type(4)));
typedef unsigned short u16x8 __attribute__((ext_vector_type(8)));

#define GLL16(gp, lp) __builtin_amdgcn_global_load_lds( \
    (__attribute__((address_space(1))) const unsigned int*)(gp), \
    (__attribute__((address_space(3))) unsigned int*)(lp), 16, 0, 0)

static __device__ __forceinline__ u16 f2bf(float f){
  unsigned u = __builtin_bit_cast(unsigned, f);
  u += 0x7fffu + ((u >> 16) & 1u);   // RNE
  return (u16)(u >> 16);
}

// ---------------- transpose + convert: dst[b][c][r] = bf16(src[b][r][c]), r zero-padded to Rpad
__global__ void transpose_f32(const float* __restrict__ src, u16* __restrict__ dst,
                              int R, int C, int Rpad, long sB, long dB){
  __shared__ u16 tile[32][33];
  const int b = blockIdx.z;
  src += (long)b*sB; dst += (long)b*dB;
  const int r0 = blockIdx.x*32, c0 = blockIdx.y*32;
  const int j = threadIdx.x & 31, i0 = threadIdx.x >> 5;
  #pragma unroll
  for (int ii=0; ii<32; ii+=8){
    int r = r0+i0+ii, c = c0+j;
    u16 v = 0;
    if (r < R && c < C) v = f2bf(src[(long)r*C + c]);
    tile[i0+ii][j] = v;
  }
  __syncthreads();
  #pragma unroll
  for (int ii=0; ii<32; ii+=8){
    int c = c0+i0+ii, r = r0+j;
    if (c < C && r < Rpad) dst[(long)c*Rpad + r] = tile[j][i0+ii];
  }
}

__global__ void transpose_u16(const u16* __restrict__ src, u16* __restrict__ dst,
                              int R, int C, int Rpad, long sB, long dB){
  __shared__ u16 tile[32][33];
  const int b = blockIdx.z;
  src += (long)b*sB; dst += (long)b*dB;
  const int r0 = blockIdx.x*32, c0 = blockIdx.y*32;
  const int j = threadIdx.x & 31, i0 = threadIdx.x >> 5;
  #pragma unroll
  for (int ii=0; ii<32; ii+=8){
    int r = r0+i0+ii, c = c0+j;
    u16 v = 0;
    if (r < R && c < C) v = src[(long)r*C + c];
    tile[i0+ii][j] = v;
  }
  __syncthreads();
  #pragma unroll
  for (int ii=0; ii<32; ii+=8){
    int c = c0+i0+ii, r = r0+j;
    if (c < C && r < Rpad) dst[(long)c*Rpad + r] = tile[j][i0+ii];
  }
}

// ---------------- G1: edges[b,e,d] = sum_n H[b,e,n]*ori[b,n,d]  tile 64x256, grid 500
// Also emits HT[b][n][e] = bf16(H[b][e][n]) via k-major LDS staging.
__global__ __launch_bounds__(256,3) void g1_kernel(
    const float* __restrict__ Hm, const u16* __restrict__ oriT,
    u16* __restrict__ edges, u16* __restrict__ HT){
  __shared__ u16 As[2][64*32];
  __shared__ u16 Bs[2][256*32];
  __shared__ u16 At[2][32*66];       // k-major, pitch 66: bank = c*33%32 = c -> conflict-free
  const int b = blockIdx.y, bm = blockIdx.x*64;
  const int tid = threadIdx.x;
  const int w = tid>>6, quad = (tid&63)>>4, l16 = tid&15;
  const int wn = w*64;
  const float* Ab = Hm + (size_t)b*8000*2000 + (size_t)bm*2000;
  const u16*  Bb = oriT + (size_t)b*256*2048;
  u16* HTb = HT + (size_t)b*2048*8000;

  float4 pa[2];
  auto loadA = [&](int kt){
    const int k0 = kt*32;
    #pragma unroll
    for (int i=0;i<2;i++){
      int idx = i*256+tid, row = idx>>3, c4 = (idx&7)*4;
      bool ok = (k0+c4 < 2000);
      pa[i] = ok ? *(const float4*)(Ab + (size_t)row*2000 + k0+c4) : make_float4(0.f,0.f,0.f,0.f);
    }
  };
  auto storeA = [&](int kt){
    const int buf = kt&1;
    #pragma unroll
    for (int i=0;i<2;i++){
      int idx = i*256+tid, row = idx>>3, c4 = (idx&7)*4;
      ushort4 o; o.x=f2bf(pa[i].x); o.y=f2bf(pa[i].y); o.z=f2bf(pa[i].z); o.w=f2bf(pa[i].w);
      *(ushort4*)(&As[buf][idx*4]) = o;
      At[buf][(c4+0)*66 + row] = o.x;
      At[buf][(c4+1)*66 + row] = o.y;
      At[buf][(c4+2)*66 + row] = o.z;
      At[buf][(c4+3)*66 + row] = o.w;
    }
  };
  auto stageB = [&](int kt){
    const int buf = kt&1, k0 = kt*32;
    #pragma unroll
    for (int i=0;i<4;i++){
      int idx = i*256+tid, row = idx>>2, c8 = (idx&3)*8;
      GLL16(Bb + (size_t)row*2048 + k0+c8, &Bs[buf][(i*256 + w*64)*8]);
    }
  };

  f32x4 acc[4][4];
  #pragma unroll
  for (int i=0;i<4;i++)
    #pragma unroll
    for (int j=0;j<4;j++) acc[i][j] = (f32x4){0.f,0.f,0.f,0.f};

  loadA(0); stageB(0);
  for (int kt=0; kt<63; kt++){       // k 2016..2047 all-zero A: skipped (HT tail rows unused)
    storeA(kt);
    __syncthreads();
    if (kt+1 < 63){ loadA(kt+1); stageB(kt+1); }
    const int buf = kt&1, k0 = kt*32;
    { // HT write: 32(k) x 64(m), conflict-free b128 reads, 128B-coalesced stores
      int kk = tid>>3, c = tid&7, m0 = c*8;
      u16x8 v = *(const u16x8*)(&At[buf][kk*66 + m0]);
      *(u16x8*)(HTb + (size_t)(k0+kk)*8000 + bm + m0) = v;
    }
    bf16x8 af[4], bf[4];
    #pragma unroll
    for (int mi=0;mi<4;mi++) af[mi] = *(const bf16x8*)(&As[buf][(mi*16+l16)*32 + quad*8]);
    #pragma unroll
    for (int ni=0;ni<4;ni++) bf[ni] = *(const bf16x8*)(&Bs[buf][(wn+ni*16+l16)*32 + quad*8]);
    #pragma unroll
    for (int mi=0;mi<4;mi++)
      #pragma unroll
      for (int ni=0;ni<4;ni++)
        acc[mi][ni] = __builtin_amdgcn_mfma_f32_16x16x32_bf16(af[mi], bf[ni], acc[mi][ni], 0,0,0);
  }
  #pragma unroll
  for (int mi=0;mi<4;mi++){
    #pragma unroll
    for (int r=0;r<4;r++){
      int gm = bm + mi*16 + quad*4 + r;
      u16* dst = edges + ((size_t)b*8000 + gm)*256;
      #pragma unroll
      for (int ni=0;ni<4;ni++) dst[wn + ni*16 + l16] = f2bf(acc[mi][ni][r]);
    }
  }
}

// ---------------- M1: H1[t,m,h] = relu(edges[m,:]@W1T[t][h,:] + b1) * ed[m,t]
__global__ __launch_bounds__(256,2) void m1_kernel(
    const u16* __restrict__ edges, const u16* __restrict__ W1T,
    const float* __restrict__ b1, const float* __restrict__ edist, u16* __restrict__ H1){
  __shared__ u16 As[2][128*32];
  __shared__ u16 Bs[2][128*32];
  __shared__ float eds[128], b1s[128];
  const int t = blockIdx.y, bm = blockIdx.x*128;
  const int tid = threadIdx.x;
  const int w = tid>>6, quad = (tid&63)>>4, l16 = tid&15;
  const int wm = (w&1)*64, wn = (w>>1)*64;
  if (tid < 128){ eds[tid] = edist[(size_t)(bm+tid)*5 + t]; b1s[tid] = b1[t*128+tid]; }
  const u16* Ab = edges + (size_t)bm*256;
  const u16* Bb = W1T + (size_t)t*128*256;

  auto stage = [&](int kt){
    const int buf = kt&1, k0 = kt*32;
    #pragma unroll
    for (int i=0;i<2;i++){
      int idx = i*256+tid, row = idx>>2, c8 = (idx&3)*8;
      GLL16(Ab + (size_t)row*256 + k0+c8, &As[buf][(i*256 + w*64)*8]);
      GLL16(Bb + (size_t)row*256 + k0+c8, &Bs[buf][(i*256 + w*64)*8]);
    }
  };

  f32x4 acc[4][4];
  #pragma unroll
  for (int i=0;i<4;i++)
    #pragma unroll
    for (int j=0;j<4;j++) acc[i][j] = (f32x4){0.f,0.f,0.f,0.f};

  stage(0);
  for (int kt=0; kt<8; kt++){
    __syncthreads();
    if (kt+1 < 8) stage(kt+1);
    const int buf = kt&1;
    bf16x8 af[4], bf[4];
    #pragma unroll
    for (int mi=0;mi<4;mi++) af[mi] = *(const bf16x8*)(&As[buf][(wm+mi*16+l16)*32 + quad*8]);
    #pragma unroll
    for (int ni=0;ni<4;ni++) bf[ni] = *(const bf16x8*)(&Bs[buf][(wn+ni*16+l16)*32 + quad*8]);
    #pragma unroll
    for (int mi=0;mi<4;mi++)
      #pragma unroll
      for (int ni=0;ni<4;ni++)
        acc[mi][ni] = __builtin_amdgcn_mfma_f32_16x16x32_bf16(af[mi], bf[ni], acc[mi][ni], 0,0,0);
  }
  #pragma unroll
  for (int mi=0;mi<4;mi++){
    #pragma unroll
    for (int r=0;r<4;r++){
      int lrow = wm + mi*16 + quad*4 + r;
      float s = eds[lrow];
      u16* dst = H1 + ((size_t)t*32000 + bm + lrow)*128;
      #pragma unroll
      for (int ni=0;ni<4;ni++){
        int lc = wn + ni*16 + l16;
        float v = fmaxf(acc[mi][ni][r] + b1s[lc], 0.f) * s;
        dst[lc] = f2bf(v);
      }
    }
  }
}

// ---------------- M2: EF[m,d] = sum_{t,h} H1[t,m,h]*W2T[t][d,h] + sum_t ed[m,t]*b2[t,d]
__global__ __launch_bounds__(256,2) void m2_kernel(
    const u16* __restrict__ H1, const u16* __restrict__ W2T,
    const float* __restrict__ b2, const float* __restrict__ edist, u16* __restrict__ EF){
  __shared__ u16 As[2][128*32];
  __shared__ u16 Bs[2][128*32];
  __shared__ float eds[640], b2s[640];
  const int bm = blockIdx.x*128, bn = blockIdx.y*128;
  const int tid = threadIdx.x;
  const int w = tid>>6, quad = (tid&63)>>4, l16 = tid&15;
  const int wm = (w&1)*64, wn = (w>>1)*64;
  for (int i=tid;i<640;i+=256){
    eds[i] = edist[(size_t)bm*5 + i];
    b2s[i] = b2[(i>>7)*256 + bn + (i&127)];
  }
  auto stage = [&](int kt){
    const int buf = kt&1, t = kt>>2, k0 = (kt&3)*32;
    #pragma unroll
    for (int i=0;i<2;i++){
      int idx = i*256+tid, row = idx>>2, c8 = (idx&3)*8;
      GLL16(H1 + ((size_t)t*32000 + bm+row)*128 + k0+c8, &As[buf][(i*256 + w*64)*8]);
      GLL16(W2T + ((size_t)t*256 + bn+row)*128 + k0+c8, &Bs[buf][(i*256 + w*64)*8]);
    }
  };

  f32x4 acc[4][4];
  #pragma unroll
  for (int i=0;i<4;i++)
    #pragma unroll
    for (int j=0;j<4;j++) acc[i][j] = (f32x4){0.f,0.f,0.f,0.f};

  stage(0);
  for (int kt=0; kt<20; kt++){
    __syncthreads();
    if (kt+1 < 20) stage(kt+1);
    const int buf = kt&1;
    bf16x8 af[4], bf[4];
    #pragma unroll
    for (int mi=0;mi<4;mi++) af[mi] = *(const bf16x8*)(&As[buf][(wm+mi*16+l16)*32 + quad*8]);
    #pragma unroll
    for (int ni=0;ni<4;ni++) bf[ni] = *(const bf16x8*)(&Bs[buf][(wn+ni*16+l16)*32 + quad*8]);
    #pragma unroll
    for (int mi=0;mi<4;mi++)
      #pragma unroll
      for (int ni=0;ni<4;ni++)
        acc[mi][ni] = __builtin_amdgcn_mfma_f32_16x16x32_bf16(af[mi], bf[ni], acc[mi][ni], 0,0,0);
  }
  #pragma unroll
  for (int mi=0;mi<4;mi++){
    #pragma unroll
    for (int r=0;r<4;r++){
      int lrow = wm + mi*16 + quad*4 + r;
      float e0=eds[lrow*5+0], e1=eds[lrow*5+1], e2=eds[lrow*5+2], e3=eds[lrow*5+3], e4=eds[lrow*5+4];
      u16* dst = EF + (size_t)(bm+lrow)*256 + bn;
      #pragma unroll
      for (int ni=0;ni<4;ni++){
        int lc = wn + ni*16 + l16;
        float bias = e0*b2s[lc] + e1*b2s[128+lc] + e2*b2s[256+lc] + e3*b2s[384+lc] + e4*b2s[512+lc];
        dst[lc] = f2bf(acc[mi][ni][r] + bias);
      }
    }
  }
}

// ---------------- G3: part[b,ks][m,d] = sum_{e slice} HT[b,m,e]*EFt[b,d,e]  tile 64x256
__global__ __launch_bounds__(256,3) void g3_kernel(
    const u16* __restrict__ HT, const u16* __restrict__ EFt, float* __restrict__ part){
  __shared__ u16 As[2][64*32];
  __shared__ u16 Bs[2][256*32];
  const int bm = blockIdx.x*64, ks = blockIdx.y, b = blockIdx.z;
  const int tid = threadIdx.x;
  const int w = tid>>6, quad = (tid&63)>>4, l16 = tid&15;
  const int wn = w*64;
  const u16* Ab = HT + (size_t)b*2048*8000 + (size_t)bm*8000;
  const u16* Bb = EFt + (size_t)b*256*8000;
  const int it0 = (250*ks)/4, it1 = (250*(ks+1))/4;

  auto stage = [&](int kt){
    const int buf = kt&1, k0 = kt*32;
    {
      int row = tid>>2, c8 = (tid&3)*8;
      GLL16(Ab + (size_t)row*8000 + k0+c8, &As[buf][(w*64)*8]);
    }
    #pragma unroll
    for (int i=0;i<4;i++){
      int idx = i*256+tid, row = idx>>2, c8 = (idx&3)*8;
      GLL16(Bb + (size_t)row*8000 + k0+c8, &Bs[buf][(i*256 + w*64)*8]);
    }
  };

  f32x4 acc[4][4];
  #pragma unroll
  for (int i=0;i<4;i++)
    #pragma unroll
    for (int j=0;j<4;j++) acc[i][j] = (f32x4){0.f,0.f,0.f,0.f};

  stage(it0);
  for (int kt=it0; kt<it1; kt++){
    __syncthreads();
    if (kt+1 < it1) stage(kt+1);
    const int buf = kt&1;
    bf16x8 af[4], bf[4];
    #pragma unroll
    for (int mi=0;mi<4;mi++) af[mi] = *(const bf16x8*)(&As[buf][(mi*16+l16)*32 + quad*8]);
    #pragma unroll
    for (int ni=0;ni<4;ni++) bf[ni] = *(const bf16x8*)(&Bs[buf][(wn+ni*16+l16)*32 + quad*8]);
    #pragma unroll
    for (int mi=0;mi<4;mi++)
      #pragma unroll
      for (int ni=0;ni<4;ni++)
        acc[mi][ni] = __builtin_amdgcn_mfma_f32_16x16x32_bf16(af[mi], bf[ni], acc[mi][ni], 0,0,0);
  }
  float* dst0 = part + ((size_t)(b*4 + ks)*2048)*256;
  #pragma unroll
  for (int mi=0;mi<4;mi++){
    #pragma unroll
    for (int r=0;r<4;r++){
      int gm = bm + mi*16 + quad*4 + r;
      float* dst = dst0 + (size_t)gm*256;
      #pragma unroll
      for (int ni=0;ni<4;ni++) dst[wn + ni*16 + l16] = acc[mi][ni][r];
    }
  }
}

// ---------------- assemble: out[b,n,:256] = sum_ks part ; out[b,n,256:] = ori[b,n,:]
__global__ void assemble_kernel(const float* __restrict__ part, const float* __restrict__ ori,
                                float* __restrict__ out){
  const int b = blockIdx.y;
  int u = blockIdx.x*256 + threadIdx.x;
  int n = u>>6, c4 = (u&63)*4;
  f32x4 s = (f32x4){0.f,0.f,0.f,0.f};
  #pragma unroll
  for (int ks=0; ks<4; ks++)
    s += *(const f32x4*)(part + ((size_t)(b*4+ks)*2048 + n)*256 + c4);
  float* dst = out + ((size_t)(b*2000+n))*512;
  *(f32x4*)(dst + c4) = s;
  *(f32x4*)(dst + 256 + c4) = *(const f32x4*)(ori + ((size_t)(b*2000+n))*256 + c4);
}

extern "C" void kernel_launch(void* const* d_in, const int* in_sizes, int n_in,
                              void* d_out, int out_size, void* d_ws, size_t ws_size,
                              hipStream_t stream) {
  const float* ed  = (const float*)d_in[0];
  const float* Hm  = (const float*)d_in[1];
  const float* ori = (const float*)d_in[2];
  const float* W1  = (const float*)d_in[3];
  const float* b1  = (const float*)d_in[4];
  const float* W2  = (const float*)d_in[5];
  const float* b2  = (const float*)d_in[6];
  float* out = (float*)d_out;
  char* ws = (char*)d_ws;

  u16* HT    = (u16*)(ws);                 // 4*2048*8000*2 = 131,072,000
  u16* oriT  = (u16*)(ws + 131072000);     // 4,194,304
  u16* W1T   = (u16*)(ws + 135266304);     //   327,680
  u16* W2T   = (u16*)(ws + 135593984);     //   327,680
  u16* edges = (u16*)(ws + 135921664);     // 16,384,000 (reused as EFt)
  u16* H1    = (u16*)(ws + 152305664);     // 40,960,000 (reused as part)
  u16* EF    = (u16*)(ws + 193265664);     // 16,384,000
  u16* EFt   = edges;
  float* part = (float*)H1;                // 33,554,432 <= 40,960,000

  hipLaunchKernelGGL(transpose_f32, dim3(64,8,4), dim3(256), 0, stream,
                     ori, oriT, 2000, 256, 2048, 512000L, 524288L);
  hipLaunchKernelGGL(transpose_f32, dim3(8,4,5), dim3(256), 0, stream,
                     W1, W1T, 256, 128, 256, 32768L, 32768L);
  hipLaunchKernelGGL(transpose_f32, dim3(4,8,5), dim3(256), 0, stream,
                     W2, W2T, 128, 256, 128, 32768L, 32768L);

  hipLaunchKernelGGL(g1_kernel, dim3(125,4), dim3(256), 0, stream, Hm, oriT, edges, HT);
  hipLaunchKernelGGL(m1_kernel, dim3(250,5), dim3(256), 0, stream, edges, W1T, b1, ed, H1);
  hipLaunchKernelGGL(m2_kernel, dim3(250,2), dim3(256), 0, stream, H1, W2T, b2, ed, EF);
  hipLaunchKernelGGL(transpose_u16, dim3(250,8,4), dim3(256), 0, stream,
                     EF, EFt, 8000, 256, 8000, 2048000L, 2048000L);
  hipLaunchKernelGGL(g3_kernel, dim3(32,4,4), dim3(256), 0, stream, HT, EFt, part);
  hipLaunchKernelGGL(assemble_kernel, dim3(500,4), dim3(256), 0, stream, part, ori, out);

  (void)in_sizes; (void)n_in; (void)ws_size;
}